// Round 1
// baseline (710.929 us; speedup 1.0000x reference)
//
#include <hip/hip_runtime.h>

#define NUM_C 1000
#define COLS4 250      // 1000 floats / 4 per float4
#define GAMMA 0.9f

typedef float v4f __attribute__((ext_vector_type(4)));   // clang-native vec4

// --- 1. histogram of labels + per-row rank ---------------------------------
// rank[i] = position of row i within its class (old value of the counter).
// Removes the need for a second atomic pass in scatter.
__global__ void count_rank_kernel(const int* __restrict__ labels,
                                  int* __restrict__ counts,
                                  int* __restrict__ rank, int n) {
    int i = blockIdx.x * blockDim.x + threadIdx.x;
    if (i < n) {
        int l = labels[i];
        rank[i] = atomicAdd(&counts[l], 1);
    }
}

// --- 2. exclusive prefix sum over 1000 counts (single block) ---------------
__global__ void scan_kernel(const int* __restrict__ counts,
                            int* __restrict__ offsets) {
    __shared__ int s[1024];
    int tid = threadIdx.x;
    int v = (tid < NUM_C) ? counts[tid] : 0;
    s[tid] = v;
    __syncthreads();
    for (int d = 1; d < 1024; d <<= 1) {
        int x = (tid >= d) ? s[tid - d] : 0;
        __syncthreads();
        s[tid] += x;
        __syncthreads();
    }
    if (tid < NUM_C) offsets[tid] = s[tid] - v;   // exclusive
}

// --- 3. scatter row indices into class buckets (no atomics) -----------------
__global__ void scatter_kernel(const int* __restrict__ labels,
                               const int* __restrict__ offsets,
                               const int* __restrict__ rank,
                               int* __restrict__ rowidx, int n) {
    int i = blockIdx.x * blockDim.x + threadIdx.x;
    if (i < n) {
        rowidx[offsets[labels[i]] + rank[i]] = i;
    }
}

// --- 4. per-class column accumulation + EMA ---------------------------------
// grid NUM_C, block 512 (8 waves). Half-block 0 handles even staged rows,
// half-block 1 handles odd rows; per-lane 4-deep unrolled loads.
// 1000 blocks x 8 waves = 8000 waves -> fills the 8192-wave machine.
__global__ __launch_bounds__(512) void accum_kernel(
        const float* __restrict__ preds, const float* __restrict__ val,
        const int* __restrict__ counts, const int* __restrict__ offsets,
        const int* __restrict__ rowidx, float* __restrict__ out) {
    const int c    = blockIdx.x;
    const int tid  = threadIdx.x;
    const int half = tid >> 8;          // 0 or 1
    const int lane = tid & 255;
    const bool active = (lane < COLS4);
    const int col4 = active ? lane : 0;  // clamp inactive lanes to safe column

    const v4f* __restrict__ pv = (const v4f*)preds;
    const v4f* __restrict__ vv = (const v4f*)val;
    v4f* __restrict__ ov = (v4f*)out;
    const size_t crow = (size_t)c * COLS4;

    const int nc  = counts[c];
    const int off = offsets[c];

    if (nc == 0) {            // empty class: passthrough val_preds
        if (half == 0 && active) ov[crow + col4] = vv[crow + col4];
        return;
    }

    __shared__ int rows_s[512];
    __shared__ v4f red[COLS4];          // cross-half reduction buffer

    v4f acc0 = {0.f, 0.f, 0.f, 0.f};
    v4f acc1 = {0.f, 0.f, 0.f, 0.f};

    for (int base = 0; base < nc; base += 512) {
        int m = min(nc - base, 512);
        if (tid < m) rows_s[tid] = rowidx[off + base + tid];
        __syncthreads();

        // this half processes rows half, half+2, half+4, ... < m
        int r = half;
        for (; r + 6 < m; r += 8) {
            size_t i0 = (size_t)rows_s[r + 0] * COLS4 + col4;
            size_t i1 = (size_t)rows_s[r + 2] * COLS4 + col4;
            size_t i2 = (size_t)rows_s[r + 4] * COLS4 + col4;
            size_t i3 = (size_t)rows_s[r + 6] * COLS4 + col4;
            v4f v0 = pv[i0];
            v4f v1 = pv[i1];
            v4f v2 = pv[i2];
            v4f v3 = pv[i3];
            acc0 += v0 + v1;
            acc1 += v2 + v3;
        }
        for (; r < m; r += 2) {
            size_t i0 = (size_t)rows_s[r] * COLS4 + col4;
            acc0 += pv[i0];
        }
        __syncthreads();
    }

    v4f acc = acc0 + acc1;
    if (half == 1 && active) red[col4] = acc;
    __syncthreads();
    if (half == 0 && active) {
        float inv = 1.0f / (float)nc;
        v4f s = acc + red[col4];
        v4f vp = vv[crow + col4];
        v4f o = (1.0f - GAMMA) * (s * inv) + GAMMA * vp;
        ov[crow + col4] = o;
    }
}

extern "C" void kernel_launch(void* const* d_in, const int* in_sizes, int n_in,
                              void* d_out, int out_size, void* d_ws, size_t ws_size,
                              hipStream_t stream) {
    const float* preds  = (const float*)d_in[0];
    const int*   labels = (const int*)d_in[1];
    const float* val    = (const float*)d_in[2];
    float*       out    = (float*)d_out;
    const int n = in_sizes[1];   // 131072 rows

    // workspace layout: counts[1024] | offsets[1024] | rank[n] | rowidx[n]
    char* ws = (char*)d_ws;
    int* counts  = (int*)(ws + 0);
    int* offsets = (int*)(ws + 4096);
    int* rank    = (int*)(ws + 8192);
    int* rowidx  = (int*)(ws + 8192 + (size_t)n * 4);

    (void)hipMemsetAsync(d_ws, 0, 4096, stream);   // zero counts only
    count_rank_kernel<<<(n + 255) / 256, 256, 0, stream>>>(labels, counts, rank, n);
    scan_kernel<<<1, 1024, 0, stream>>>(counts, offsets);
    scatter_kernel<<<(n + 255) / 256, 256, 0, stream>>>(labels, offsets, rank, rowidx, n);
    accum_kernel<<<NUM_C, 512, 0, stream>>>(preds, val, counts, offsets, rowidx, out);
}

// Round 2
// 703.576 us; speedup vs baseline: 1.0105x; 1.0105x over previous
//
#include <hip/hip_runtime.h>

#define NUM_C 1000
#define COLS4 250      // 1000 floats / 4 per float4
#define GAMMA 0.9f
#define CAP   8192     // LDS row-list capacity (expected nc ~131, max ~200)

typedef float v4f __attribute__((ext_vector_type(4)));   // clang-native vec4

// Single fused kernel: one block per class.
// Phase 1: scan labels (L2-resident, 524 KB), append matching row indices to
//          an LDS list (block-local atomics, ~131 appends per block).
// Phase 2: gather those rows of preds (each row = 4000 B, fully coalesced
//          across 250 float4 lanes) and accumulate; EMA epilogue.
// Halves of the 512-thread block split the row list even/odd for 2x MLP.
__global__ __launch_bounds__(512) void fused_kernel(
        const float* __restrict__ preds, const int* __restrict__ labels,
        const float* __restrict__ val, float* __restrict__ out, int n) {
    const int c    = blockIdx.x;
    const int tid  = threadIdx.x;
    const int half = tid >> 8;          // 0 or 1
    const int lane = tid & 255;
    const bool active = (lane < COLS4);
    const int col4 = active ? lane : 0; // clamp inactive lanes to safe column

    __shared__ int cnt;
    __shared__ int rows_s[CAP];
    __shared__ v4f red[COLS4];          // cross-half reduction buffer

    if (tid == 0) cnt = 0;
    __syncthreads();

    // ---- phase 1: build row list for class c -------------------------------
    {
        const int n4 = n >> 2;                        // vectorized label scan
        const int4* __restrict__ lab4 = (const int4*)labels;
        for (int i = tid; i < n4; i += 512) {
            int4 L = lab4[i];
            int b = i << 2;
            if (L.x == c) { int p = atomicAdd(&cnt, 1); if (p < CAP) rows_s[p] = b + 0; }
            if (L.y == c) { int p = atomicAdd(&cnt, 1); if (p < CAP) rows_s[p] = b + 1; }
            if (L.z == c) { int p = atomicAdd(&cnt, 1); if (p < CAP) rows_s[p] = b + 2; }
            if (L.w == c) { int p = atomicAdd(&cnt, 1); if (p < CAP) rows_s[p] = b + 3; }
        }
        for (int i = (n & ~3) + tid; i < n; i += 512) {   // tail (n%4 != 0)
            if (labels[i] == c) { int p = atomicAdd(&cnt, 1); if (p < CAP) rows_s[p] = i; }
        }
    }
    __syncthreads();
    const int nc = cnt;

    const v4f* __restrict__ pv = (const v4f*)preds;
    const v4f* __restrict__ vv = (const v4f*)val;
    v4f* __restrict__ ov = (v4f*)out;
    const size_t crow = (size_t)c * COLS4;

    if (nc == 0) {            // empty class: passthrough val_preds
        if (half == 0 && active) ov[crow + col4] = vv[crow + col4];
        return;
    }

    v4f acc0 = {0.f, 0.f, 0.f, 0.f};
    v4f acc1 = {0.f, 0.f, 0.f, 0.f};

    if (nc <= CAP) {
        // ---- phase 2 (fast): gather listed rows; halves take even/odd ------
        int r = half;
        for (; r + 6 < nc; r += 8) {
            size_t i0 = (size_t)rows_s[r + 0] * COLS4 + col4;
            size_t i1 = (size_t)rows_s[r + 2] * COLS4 + col4;
            size_t i2 = (size_t)rows_s[r + 4] * COLS4 + col4;
            size_t i3 = (size_t)rows_s[r + 6] * COLS4 + col4;
            v4f v0 = pv[i0];
            v4f v1 = pv[i1];
            v4f v2 = pv[i2];
            v4f v3 = pv[i3];
            acc0 += v0 + v1;
            acc1 += v2 + v3;
        }
        for (; r < nc; r += 2) {
            acc0 += pv[(size_t)rows_s[r] * COLS4 + col4];
        }
    } else {
        // ---- phase 2 (slow, never expected): direct predicated scan --------
        for (int i = half; i < n; i += 2) {
            if (labels[i] == c) acc0 += pv[(size_t)i * COLS4 + col4];
        }
    }

    // ---- cross-half reduce + EMA epilogue ----------------------------------
    v4f acc = acc0 + acc1;
    if (half == 1 && active) red[col4] = acc;
    __syncthreads();
    if (half == 0 && active) {
        float inv = 1.0f / (float)nc;
        v4f s = acc + red[col4];
        v4f vp = vv[crow + col4];
        v4f o = (1.0f - GAMMA) * (s * inv) + GAMMA * vp;
        ov[crow + col4] = o;
    }
}

extern "C" void kernel_launch(void* const* d_in, const int* in_sizes, int n_in,
                              void* d_out, int out_size, void* d_ws, size_t ws_size,
                              hipStream_t stream) {
    const float* preds  = (const float*)d_in[0];
    const int*   labels = (const int*)d_in[1];
    const float* val    = (const float*)d_in[2];
    float*       out    = (float*)d_out;
    const int n = in_sizes[1];   // 131072 rows

    fused_kernel<<<NUM_C, 512, 0, stream>>>(preds, labels, val, out, n);
}